// Round 1
// 15884.665 us; speedup vs baseline: 1.0661x; 1.0661x over previous
//
#include <hip/hip_runtime.h>

// TinyRNNPolicy: h_{t+1} = tanh(W h_t); action_t = tanh(mean(h_{t+1}[:2048]))
//
// R4: flag-free step exchange. Writers publish h as ~bit_cast<uint>(h)
// (bit-exact; ~bits==0 only for NaN 0xFFFFFFFF which tanh never makes);
// readers spin directly on their 4 h dwords != 0 -- fuses the old
// {vmcnt drain -> flag store -> flag spin -> h load} (2 cross-XCD hops +
// drain) into ONE hop. Validity across reuse: 3-buffer rotation, owner
// clears its segment of the buffer read at iter s-1 (rewritten at s+1,
// re-read at s+2). The vmcnt(0) before each h-store orders clear<h-store
// so any reader that sees fresh h also sees the clear. Skew is <1 iter
// by construction (spin = full data dependency). One legacy flag barrier
// after the loop makes 'parts' stores visible to the output phase.
//
// W slice (16 rows x 4096) stays pinned in VGPRs (64 floats/thread, asm
// register barrier). 256 blocks x 1024 threads, 1 block/CU.

#define N 4096
#define HALF 2048
#define BLOCKS 256
#define TPB 1024
#define RPB 16        // rows per block
#define CCOLS 64      // cols per thread-chunk
#define NCH 64        // chunks (4096/64)
#define PAD 68        // LDS chunk stride (68%32==4 -> conflict-free groups)

// ws layout (dword offsets); ws re-poisoned 0xAA each launch -> init kernel.
#define WS_FLAGS 0            // 256 flags, stride 16 dwords (64B lines)
#define WS_HA    4096         // h buffer 0 (encoded ~bits)
#define WS_HB    8192         // h buffer 1
#define WS_HC    12288        // h buffer 2
#define WS_ACC   16384        // accum[out_size] (fallback path only)
#define WS_PART  20480        // parts[n_steps*128] (big path)

__device__ __forceinline__ float agent_ld(const float* p) {
    return __hip_atomic_load(p, __ATOMIC_RELAXED, __HIP_MEMORY_SCOPE_AGENT);
}
__device__ __forceinline__ void agent_st(float* p, float v) {
    __hip_atomic_store(p, v, __ATOMIC_RELAXED, __HIP_MEMORY_SCOPE_AGENT);
}
__device__ __forceinline__ unsigned agent_ldu(const unsigned* p) {
    return __hip_atomic_load(p, __ATOMIC_RELAXED, __HIP_MEMORY_SCOPE_AGENT);
}
__device__ __forceinline__ void agent_stu(unsigned* p, unsigned v) {
    __hip_atomic_store(p, v, __ATOMIC_RELAXED, __HIP_MEMORY_SCOPE_AGENT);
}

__device__ __forceinline__ float tanh_fast(float x) {
    x = fminf(fmaxf(x, -15.0f), 15.0f);   // clamp avoids inf/inf
    float e = __expf(2.0f * x);
    return (e - 1.0f) / (e + 1.0f);       // exact 0 at x==0
}

__global__ void rnn_init(const float* __restrict__ h0, float* __restrict__ ws, int n_out) {
    int i = blockIdx.x * blockDim.x + threadIdx.x;
    if (i < BLOCKS * 16) agent_stu((unsigned*)ws + WS_FLAGS + i, 0u);
    if (i < n_out) agent_st(ws + WS_ACC + i, 0.0f);
    if (i < N) {
        agent_stu((unsigned*)ws + WS_HA + i, ~__float_as_uint(h0[i]));  // encoded h0
        agent_stu((unsigned*)ws + WS_HB + i, 0u);                       // invalid
        agent_stu((unsigned*)ws + WS_HC + i, 0u);                       // invalid
    }
}

__global__ void __launch_bounds__(TPB, 4)
rnn_persistent(const float* __restrict__ W, const int* __restrict__ pns,
               float* __restrict__ out, float* __restrict__ ws, int big) {
    const int b = blockIdx.x;
    const int t = threadIdx.x;
    const int lane = t & 63;
    const int wave = t >> 6;       // 0..15
    const int row = t & 15;        // row within block's 16 rows
    const int chunk = t >> 4;      // 0..63, 64-col chunk
    const int grow = b * RPB + row;

    // ---- one-time: W slice into registers, then PIN with asm barrier ----
    float w[CCOLS];
    {
        const float4* Wv = (const float4*)(W + (size_t)grow * N + (size_t)chunk * CCOLS);
#pragma unroll
        for (int i = 0; i < CCOLS / 4; ++i) {
            float4 v = Wv[i];
            w[4*i+0] = v.x; w[4*i+1] = v.y; w[4*i+2] = v.z; w[4*i+3] = v.w;
        }
    }
#pragma unroll
    for (int i = 0; i < CCOLS; ++i) asm volatile("" : "+v"(w[i]));  // pin: no remat

    const int n_steps = *pns;

    __shared__ float hs[NCH * PAD];   // padded h broadcast (~17.4 KiB)
    __shared__ float part[256];       // 16 waves x 16 rows

    unsigned* flags = (unsigned*)ws + WS_FLAGS;
    unsigned* bufA  = (unsigned*)ws + WS_HA;
    unsigned* bufB  = (unsigned*)ws + WS_HB;
    unsigned* bufC  = (unsigned*)ws + WS_HC;
    float* accum = ws + WS_ACC;
    float* parts = ws + WS_PART;

    // rotation: read rdp, write wrp, clear clp (= buffer read at s-1)
    unsigned *rdp = bufA, *wrp = bufB, *clp = bufC;

    for (int s = 0; s < n_steps; ++s) {
        // ---- fused spin + h load: wait until all 4 of my dwords valid ----
        const unsigned* src = rdp + 4 * t;
        unsigned a0, a1, a2, a3;
        {
            unsigned spins = 0;
            for (;;) {
                a0 = agent_ldu(src + 0); a1 = agent_ldu(src + 1);
                a2 = agent_ldu(src + 2); a3 = agent_ldu(src + 3);
                if (min(min(a0, a1), min(a2, a3)) != 0u) break;
                __builtin_amdgcn_s_sleep(1);
                if (++spins > (1u << 22)) break;   // fail loud, don't hang
            }
        }
        // owner invalidates its segment of the buffer read at s-1
        // (safe: my spin success => all blocks wrote s-1 => all finished
        //  reading clp; visible-before-reuse: drained by vmcnt(0) below)
        if (t < RPB) agent_stu(clp + b * RPB + t, 0u);

        {
            int base = (t >> 4) * PAD + 4 * (t & 15);
            *(float4*)&hs[base] = make_float4(__uint_as_float(~a0), __uint_as_float(~a1),
                                              __uint_as_float(~a2), __uint_as_float(~a3));
        }
        __syncthreads();

        // fallback path: accum[s-1] adds are all drained (pre-vmcnt of s-1)
        if (!big && b == 0 && t == 0 && s > 0)
            out[s-1] = tanh_fast(agent_ld(accum + s - 1) * (1.0f / (float)HALF));

        // ---- 64 FMAs over this thread's chunk (16-lane broadcast reads) ----
        float s0 = 0.f, s1 = 0.f, s2 = 0.f, s3 = 0.f;
        const int hb = chunk * PAD;
#pragma unroll
        for (int k = 0; k < CCOLS; k += 4) {
            float4 hv = *(const float4*)&hs[hb + k];
            s0 = fmaf(w[k+0], hv.x, s0);
            s1 = fmaf(w[k+1], hv.y, s1);
            s2 = fmaf(w[k+2], hv.z, s2);
            s3 = fmaf(w[k+3], hv.w, s3);
        }
        float v = (s0 + s1) + (s2 + s3);

        // ---- intra-wave reduce: wave's 4 chunks -> lanes 0..15 (16 rows) ----
        v += __shfl_down(v, 32);
        v += __shfl_down(v, 16);
        if (lane < 16) part[wave * 16 + lane] = v;
        __syncthreads();

        // ---- wave 0: final reduce, tanh, publish encoded h (the flag IS the data)
        if (wave == 0) {
            float hval = 0.0f;
            if (t < RPB) {
                float acc = 0.0f;
#pragma unroll
                for (int c = 0; c < 16; ++c) acc += part[c * 16 + t];
                hval = tanh_fast(acc);
            }
            // readout partial: sum of this block's 16 h values
            float r = (t < RPB) ? hval : 0.0f;
            r += __shfl_down(r, 8);
            r += __shfl_down(r, 4);
            r += __shfl_down(r, 2);
            r += __shfl_down(r, 1);
            if (!big && t == 0 && b < (BLOCKS / 2)) atomicAdd(accum + s, r);
            // drain clear (+fallback atomic); h-store visibility then implies
            // clear visibility. Outstanding ops here are old -> ~free.
            asm volatile("s_waitcnt vmcnt(0)" ::: "memory");
            if (t < RPB) agent_stu(wrp + b * RPB + t, ~__float_as_uint(hval));
            if (big && t == 0 && b < (BLOCKS / 2))
                agent_st(parts + (size_t)s * 128 + b, r);   // off critical path
        }

        // rotate buffers: rdp<-wrp, wrp<-clp, clp<-rdp
        unsigned* tmp = rdp; rdp = wrp; wrp = clp; clp = tmp;
    }

    // ---- one-time device barrier so 'parts' stores are visible ----
    if (t == 0) {
        asm volatile("s_waitcnt vmcnt(0)" ::: "memory");
        agent_stu(flags + b * 16, 1u);
    }
    if (t < BLOCKS) {
        unsigned spins = 0;
        while (agent_ldu(flags + t * 16) == 0u) {
            __builtin_amdgcn_s_sleep(1);
            if (++spins > (1u << 22)) break;
        }
    }
    __syncthreads();

    if (!big) {
        if (b == 0 && t == 0)
            out[n_steps-1] = tanh_fast(agent_ld(accum + n_steps - 1) * (1.0f / (float)HALF));
    } else {
        // ---- big path: all outputs computed in parallel after the loop ----
        const int l = t & 63;
        for (int ss = b * 16 + (t >> 6); ss < n_steps; ss += BLOCKS * 16) {
            float v2 = agent_ld(parts + (size_t)ss * 128 + l)
                     + agent_ld(parts + (size_t)ss * 128 + 64 + l);
            v2 += __shfl_down(v2, 32);
            v2 += __shfl_down(v2, 16);
            v2 += __shfl_down(v2, 8);
            v2 += __shfl_down(v2, 4);
            v2 += __shfl_down(v2, 2);
            v2 += __shfl_down(v2, 1);
            if (l == 0) out[ss] = tanh_fast(v2 * (1.0f / (float)HALF));
        }
    }
}

extern "C" void kernel_launch(void* const* d_in, const int* in_sizes, int n_in,
                              void* d_out, int out_size, void* d_ws, size_t ws_size,
                              hipStream_t stream) {
    const float* W  = (const float*)d_in[0];
    const float* h0 = (const float*)d_in[1];
    const int*  pns = (const int*)d_in[2];
    float* out = (float*)d_out;
    float* ws  = (float*)d_ws;

    size_t need = ((size_t)WS_PART + (size_t)out_size * 128) * 4;
    int big = (ws_size >= need) ? 1 : 0;

    int n_init = out_size > N ? out_size : N;
    rnn_init<<<(n_init + 255) / 256, 256, 0, stream>>>(h0, ws, out_size);
    rnn_persistent<<<BLOCKS, TPB, 0, stream>>>(W, pns, out, ws, big);
}